// Round 2
// baseline (424.321 us; speedup 1.0000x reference)
//
#include <hip/hip_runtime.h>
#include <hip/hip_bf16.h>
#include <cmath>

// ---------------------------------------------------------------------------
// NPerTokenSwishGLU_Basis — compact fused f16-MFMA implementation (gfx950)
//
// Shapes: B=16, L=128, D=512, F=1024, K=16.
//
// WS-SAFETY (round-2 theory): round 1 used 62 MB of d_ws blindly and the
// post-timing check showed persistent corruption => assume ws_size may be as
// small as out bytes. This version uses EXACTLY 4,194,304 B of d_ws (Hp only).
// Racc overlays d_out (final_kernel normalizes in place). No prep kernels:
// bases are staged fp32->LDS->f16 (k-fastest) per chunk inside the consumers;
// W-norms are accumulated during the mix (sum of squares of mix-MFMA outputs)
// and applied in the epilogues; softmax computed per-block.
//
// Pipeline: up_kernel (u,v + silu fusion -> Hp f16) -> down_kernel (-> d_out
// fp32, rn3 applied) -> final_kernel (row L2-normalize in place).
// ---------------------------------------------------------------------------

typedef _Float16 half8 __attribute__((ext_vector_type(8)));
typedef _Float16 half4 __attribute__((ext_vector_type(4)));
typedef float    f32x4 __attribute__((ext_vector_type(4)));

#define MFMA_F16 __builtin_amdgcn_mfma_f32_16x16x32_f16

// ---------------------------------------------------------------------------
// up_kernel: grid = 8 l-groups x 64 f-tiles = 512 blocks, 256 threads.
// Per d-chunk(32): stage x -> Xt(f16), stage W1 basis -> Bh(f16,k-fastest),
// MFMA-mix W1 -> Wt, consume -> aU; stage W2, mix, consume -> aV.
// Epilogue: rn1/rn2 from in-loop sum-of-squares; silu/scale; write Hp.
// ---------------------------------------------------------------------------
__global__ __launch_bounds__(256) void up_kernel(
    const float* __restrict__ x,
    const float* __restrict__ wg, const float* __restrict__ wu,
    const float* __restrict__ tc1, const float* __restrict__ tc2,
    const float* __restrict__ usp, const float* __restrict__ vsp,
    _Float16* __restrict__ Hp)
{
    int lg = blockIdx.x >> 6;          // 0..7  (16 tokens each)
    int f0 = (blockIdx.x & 63) * 16;   // f-tile base
    int tid = threadIdx.x;
    int w = tid >> 6, lane = tid & 63;
    int n = lane & 15, kc = lane >> 4;

    // LDS: 20480 + 24576 + 16896 + 2048 = 64000 B  (<= 64 KB static)
    __shared__ __align__(16) _Float16 Xt[256 * 40];     // [l*16+b][d32 pad40]
    __shared__ __align__(16) _Float16 Bh[32 * 16 * 24]; // [dd][f][k pad24]
    __shared__ __align__(16) _Float16 Wt[16 * 528];     // [l][f16][d32]+pad
    __shared__ float CN[2 * 16 * 16];                   // softmax c; later nsq

    // ---- per-block softmax (c1, c2) into CN ----
    if (tid < 32) {
        int s = tid >> 4, ll = tid & 15;
        const float* row = (s ? tc2 : tc1) + (size_t)(lg * 16 + ll) * 16;
        float e[16], m = -1e30f, sum = 0.f;
#pragma unroll
        for (int k = 0; k < 16; ++k) m = fmaxf(m, row[k]);
#pragma unroll
        for (int k = 0; k < 16; ++k) { e[k] = __expf(row[k] - m); sum += e[k]; }
        float r = 1.f / sum;
#pragma unroll
        for (int k = 0; k < 16; ++k) CN[s * 256 + ll * 16 + k] = e[k] * r;
    }
    __syncthreads();

    // ---- coef B-frags (B[k][col=l] = c[l][k]) ----
    half8 cf1 = { 0, 0, 0, 0, 0, 0, 0, 0 };
    half8 cf2 = { 0, 0, 0, 0, 0, 0, 0, 0 };
    if (kc < 2) {
#pragma unroll
        for (int j = 0; j < 8; ++j) {
            cf1[j] = (_Float16)CN[0 * 256 + n * 16 + kc * 8 + j];
            cf2[j] = (_Float16)CN[1 * 256 + n * 16 + kc * 8 + j];
        }
    }

    f32x4 zf = { 0.f, 0.f, 0.f, 0.f };
    f32x4 aU[4], aV[4];
#pragma unroll
    for (int i = 0; i < 4; ++i) { aU[i] = zf; aV[i] = zf; }
    float nsqU[4] = { 0.f, 0.f, 0.f, 0.f };
    float nsqV[4] = { 0.f, 0.f, 0.f, 0.f };

    for (int it = 0; it < 16; ++it) {
        int d0 = it * 32;
        // ---- stage x chunk: [l][b][d0..d0+32) fp32 -> f16 ----
#pragma unroll
        for (int p = 0; p < 8; ++p) {
            int r = p * 32 + (tid >> 3);        // 0..255 = ll*16+b
            int fj = tid & 7;
            int ll = r >> 4, b = r & 15;
            f32x4 v = *(const f32x4*)(
                x + ((size_t)(b * 128 + lg * 16 + ll) * 512 + d0 + fj * 4));
            half4 h = { (_Float16)v[0], (_Float16)v[1],
                        (_Float16)v[2], (_Float16)v[3] };
            *(half4*)(&Xt[r * 40 + fj * 4]) = h;
        }
        // ---- stage W1 basis chunk -> Bh [dd][f][k] ----
#pragma unroll
        for (int p = 0; p < 8; ++p) {
            int idx = p * 256 + tid;
            int q = idx & 3, dd = (idx >> 2) & 31, k = idx >> 7;
            f32x4 v = *(const f32x4*)(
                wg + ((size_t)k * 512 + d0 + dd) * 1024 + f0 + q * 4);
#pragma unroll
            for (int j = 0; j < 4; ++j)
                Bh[(dd * 16 + q * 4 + j) * 24 + k] = (_Float16)v[j];
        }
        __syncthreads();
        // ---- mix W1 -> Wt (+ nsqU) ----
#pragma unroll
        for (int fl = 0; fl < 4; ++fl) {
            int f_l = w * 4 + fl;
#pragma unroll
            for (int dg = 0; dg < 2; ++dg) {
                half8 a = { 0, 0, 0, 0, 0, 0, 0, 0 };
                if (kc < 2)
                    a = *(const half8*)(&Bh[((dg * 16 + n) * 16 + f_l) * 24 + kc * 8]);
                f32x4 cw = MFMA_F16(a, cf1, zf, 0, 0, 0);
                nsqU[fl] += cw[0] * cw[0] + cw[1] * cw[1]
                          + cw[2] * cw[2] + cw[3] * cw[3];
                half4 h4 = { (_Float16)cw[0], (_Float16)cw[1],
                             (_Float16)cw[2], (_Float16)cw[3] };
                *(half4*)(&Wt[n * 528 + f_l * 32 + dg * 16 + kc * 4]) = h4;
            }
        }
        __syncthreads();
        // ---- consume U ; stage W2 basis (Bh free: mix done) ----
#pragma unroll
        for (int li = 0; li < 4; ++li) {
            int l = w * 4 + li;
            half8 xf = *(const half8*)(&Xt[(l * 16 + n) * 40 + kc * 8]);
            half8 wf = *(const half8*)(&Wt[l * 528 + n * 32 + kc * 8]);
            aU[li] = MFMA_F16(xf, wf, aU[li], 0, 0, 0);
        }
#pragma unroll
        for (int p = 0; p < 8; ++p) {
            int idx = p * 256 + tid;
            int q = idx & 3, dd = (idx >> 2) & 31, k = idx >> 7;
            f32x4 v = *(const f32x4*)(
                wu + ((size_t)k * 512 + d0 + dd) * 1024 + f0 + q * 4);
#pragma unroll
            for (int j = 0; j < 4; ++j)
                Bh[(dd * 16 + q * 4 + j) * 24 + k] = (_Float16)v[j];
        }
        __syncthreads();
        // ---- mix W2 -> Wt (+ nsqV) ----
#pragma unroll
        for (int fl = 0; fl < 4; ++fl) {
            int f_l = w * 4 + fl;
#pragma unroll
            for (int dg = 0; dg < 2; ++dg) {
                half8 a = { 0, 0, 0, 0, 0, 0, 0, 0 };
                if (kc < 2)
                    a = *(const half8*)(&Bh[((dg * 16 + n) * 16 + f_l) * 24 + kc * 8]);
                f32x4 cw = MFMA_F16(a, cf2, zf, 0, 0, 0);
                nsqV[fl] += cw[0] * cw[0] + cw[1] * cw[1]
                          + cw[2] * cw[2] + cw[3] * cw[3];
                half4 h4 = { (_Float16)cw[0], (_Float16)cw[1],
                             (_Float16)cw[2], (_Float16)cw[3] };
                *(half4*)(&Wt[n * 528 + f_l * 32 + dg * 16 + kc * 4]) = h4;
            }
        }
        __syncthreads();
        // ---- consume V ----
#pragma unroll
        for (int li = 0; li < 4; ++li) {
            int l = w * 4 + li;
            half8 xf = *(const half8*)(&Xt[(l * 16 + n) * 40 + kc * 8]);
            half8 wf = *(const half8*)(&Wt[l * 528 + n * 32 + kc * 8]);
            aV[li] = MFMA_F16(xf, wf, aV[li], 0, 0, 0);
        }
        __syncthreads();
    }

    // ---- norms: reduce over kc lanes, stash in CN (cS lifetime over) ----
#pragma unroll
    for (int fl = 0; fl < 4; ++fl) {
        float vU = nsqU[fl], vV = nsqV[fl];
        vU += __shfl_xor(vU, 16); vU += __shfl_xor(vU, 32);
        vV += __shfl_xor(vV, 16); vV += __shfl_xor(vV, 32);
        if (kc == 0) {
            CN[0 * 256 + n * 16 + w * 4 + fl] = vU;
            CN[1 * 256 + n * 16 + w * 4 + fl] = vV;
        }
    }
    __syncthreads();

    // ---- epilogue: rn1/rn2, silu, scales -> Hp f16 [l][b][f] ----
    int f = f0 + n;
    float usv = fabsf(usp[f]);
    float vsv = fabsf(vsp[f]) * 22.627416997969522f;   // sqrt(512)
#pragma unroll
    for (int li = 0; li < 4; ++li) {
        int lgl = lg * 16 + w * 4 + li;
        float r1 = 1.f / fmaxf(sqrtf(CN[0 * 256 + (w * 4 + li) * 16 + n]), 1e-12f);
        float r2 = 1.f / fmaxf(sqrtf(CN[1 * 256 + (w * 4 + li) * 16 + n]), 1e-12f);
#pragma unroll
        for (int i = 0; i < 4; ++i) {
            float u = aU[li][i] * r1;
            float v = aV[li][i] * r2;
            float zz = vsv * v;
            float sil = zz / (1.f + __expf(-zz));
            float h = sil * (usv * u);
            Hp[((size_t)lgl * 16 + kc * 4 + i) * 1024 + f] = (_Float16)h;
        }
    }
}

// ---------------------------------------------------------------------------
// down_kernel: grid = 8 l-groups x 32 d-tiles = 256 blocks, 256 threads.
// Per f-chunk(32): stage Hp -> Ht, stage W3 basis -> Bh, mix -> Wt (+nsq3),
// consume -> aO.  Epilogue applies rn3, writes d_out fp32 [b][l][d].
// ---------------------------------------------------------------------------
__global__ __launch_bounds__(256) void down_kernel(
    const float* __restrict__ wd, const float* __restrict__ tc3,
    const _Float16* __restrict__ Hp, float* __restrict__ out)
{
    int lg = blockIdx.x >> 5;          // 0..7
    int d0 = (blockIdx.x & 31) * 16;
    int tid = threadIdx.x;
    int w = tid >> 6, lane = tid & 63;
    int n = lane & 15, kc = lane >> 4;

    __shared__ __align__(16) _Float16 Ht[256 * 40];     // [l*16+b][f32 pad40]
    __shared__ __align__(16) _Float16 Bh[32 * 16 * 24]; // [ff][d][k pad24]
    __shared__ __align__(16) _Float16 Wt[16 * 528];     // [l][d16][f32]+pad
    __shared__ float CN[16 * 16];                       // c3; later nsq3

    if (tid < 16) {
        const float* row = tc3 + (size_t)(lg * 16 + tid) * 16;
        float e[16], m = -1e30f, sum = 0.f;
#pragma unroll
        for (int k = 0; k < 16; ++k) m = fmaxf(m, row[k]);
#pragma unroll
        for (int k = 0; k < 16; ++k) { e[k] = __expf(row[k] - m); sum += e[k]; }
        float r = 1.f / sum;
#pragma unroll
        for (int k = 0; k < 16; ++k) CN[tid * 16 + k] = e[k] * r;
    }
    __syncthreads();

    half8 cf3 = { 0, 0, 0, 0, 0, 0, 0, 0 };
    if (kc < 2) {
#pragma unroll
        for (int j = 0; j < 8; ++j)
            cf3[j] = (_Float16)CN[n * 16 + kc * 8 + j];
    }

    f32x4 zf = { 0.f, 0.f, 0.f, 0.f };
    f32x4 aO[4];
#pragma unroll
    for (int i = 0; i < 4; ++i) aO[i] = zf;
    float nsqD[4] = { 0.f, 0.f, 0.f, 0.f };

    for (int it = 0; it < 32; ++it) {
        int f0 = it * 32;
        // ---- stage Hp chunk (already f16) ----
#pragma unroll
        for (int p = 0; p < 8; ++p) {
            int r = p * 32 + (tid >> 3);
            int hj = tid & 7;
            int ll = r >> 4, b = r & 15;
            half4 v = *(const half4*)(
                Hp + ((size_t)(lg * 16 + ll) * 16 + b) * 1024 + f0 + hj * 4);
            *(half4*)(&Ht[r * 40 + hj * 4]) = v;
        }
        // ---- stage W3 basis chunk -> Bh [ff][d][k] ----
#pragma unroll
        for (int p = 0; p < 8; ++p) {
            int idx = p * 256 + tid;
            int q = idx & 3, ff = (idx >> 2) & 31, k = idx >> 7;
            f32x4 v = *(const f32x4*)(
                wd + ((size_t)k * 1024 + f0 + ff) * 512 + d0 + q * 4);
#pragma unroll
            for (int j = 0; j < 4; ++j)
                Bh[(ff * 16 + q * 4 + j) * 24 + k] = (_Float16)v[j];
        }
        __syncthreads();
        // ---- mix W3 -> Wt (+ nsq3) ----
#pragma unroll
        for (int dl = 0; dl < 4; ++dl) {
            int d_l = w * 4 + dl;
#pragma unroll
            for (int fg = 0; fg < 2; ++fg) {
                half8 a = { 0, 0, 0, 0, 0, 0, 0, 0 };
                if (kc < 2)
                    a = *(const half8*)(&Bh[((fg * 16 + n) * 16 + d_l) * 24 + kc * 8]);
                f32x4 cw = MFMA_F16(a, cf3, zf, 0, 0, 0);
                nsqD[dl] += cw[0] * cw[0] + cw[1] * cw[1]
                          + cw[2] * cw[2] + cw[3] * cw[3];
                half4 h4 = { (_Float16)cw[0], (_Float16)cw[1],
                             (_Float16)cw[2], (_Float16)cw[3] };
                *(half4*)(&Wt[n * 528 + d_l * 32 + fg * 16 + kc * 4]) = h4;
            }
        }
        __syncthreads();
        // ---- consume ----
#pragma unroll
        for (int li = 0; li < 4; ++li) {
            int l = w * 4 + li;
            half8 hf = *(const half8*)(&Ht[(l * 16 + n) * 40 + kc * 8]);
            half8 wf = *(const half8*)(&Wt[l * 528 + n * 32 + kc * 8]);
            aO[li] = MFMA_F16(hf, wf, aO[li], 0, 0, 0);
        }
        __syncthreads();
    }

#pragma unroll
    for (int dl = 0; dl < 4; ++dl) {
        float v = nsqD[dl];
        v += __shfl_xor(v, 16); v += __shfl_xor(v, 32);
        if (kc == 0) CN[n * 16 + w * 4 + dl] = v;
    }
    __syncthreads();

    // ---- epilogue: rn3, write out[b][l][d] fp32 (Racc overlays d_out) ----
#pragma unroll
    for (int li = 0; li < 4; ++li) {
        int lgl = lg * 16 + w * 4 + li;
        float r3 = 1.f / fmaxf(sqrtf(CN[(w * 4 + li) * 16 + n]), 1e-12f);
#pragma unroll
        for (int i = 0; i < 4; ++i)
            out[((size_t)(kc * 4 + i) * 128 + lgl) * 512 + d0 + n] = aO[li][i] * r3;
    }
}

// ---------------------------------------------------------------------------
// final_kernel: in-place row L2-normalize of d_out (2048 rows of 512).
// ---------------------------------------------------------------------------
__global__ __launch_bounds__(128) void final_kernel(float* __restrict__ out)
{
    int rid = blockIdx.x;              // b*128 + l
    int t = threadIdx.x;
    f32x4 y = *(const f32x4*)(out + (size_t)rid * 512 + t * 4);
    float s = y[0] * y[0] + y[1] * y[1] + y[2] * y[2] + y[3] * y[3];
#pragma unroll
    for (int off = 32; off > 0; off >>= 1) s += __shfl_down(s, off);
    __shared__ float sred[2];
    if ((t & 63) == 0) sred[t >> 6] = s;
    __syncthreads();
    float rr = 1.f / fmaxf(sqrtf(sred[0] + sred[1]), 1e-12f);
    f32x4 o = { y[0] * rr, y[1] * rr, y[2] * rr, y[3] * rr };
    *(f32x4*)(out + (size_t)rid * 512 + t * 4) = o;
}

// ---------------------------------------------------------------------------
extern "C" void kernel_launch(void* const* d_in, const int* in_sizes, int n_in,
                              void* d_out, int out_size, void* d_ws, size_t ws_size,
                              hipStream_t stream)
{
    (void)in_sizes; (void)n_in; (void)out_size; (void)ws_size;
    const float* x   = (const float*)d_in[0];
    const float* wg  = (const float*)d_in[1];
    const float* wu  = (const float*)d_in[2];
    const float* wd  = (const float*)d_in[3];
    const float* tc1 = (const float*)d_in[4];
    const float* tc2 = (const float*)d_in[5];
    const float* tc3 = (const float*)d_in[6];
    const float* usp = (const float*)d_in[7];
    const float* vsp = (const float*)d_in[8];

    _Float16* Hp = (_Float16*)d_ws;            // exactly 4,194,304 B used
    float* outp  = (float*)d_out;

    up_kernel<<<dim3(512), dim3(256), 0, stream>>>(x, wg, wu, tc1, tc2,
                                                   usp, vsp, Hp);
    down_kernel<<<dim3(256), dim3(256), 0, stream>>>(wd, tc3, Hp, outp);
    final_kernel<<<dim3(2048), dim3(128), 0, stream>>>(outp);
}

// Round 3
// 260.659 us; speedup vs baseline: 1.6279x; 1.6279x over previous
//
#include <hip/hip_runtime.h>
#include <hip/hip_bf16.h>
#include <cmath>

// ---------------------------------------------------------------------------
// NPerTokenSwishGLU_Basis — fused f16-MFMA implementation (gfx950), round 3.
//
// Round-2 post-mortem: SQ_LDS_BANK_CONFLICT = 8e7 (~70% of up_kernel cycles).
// Root cause: in-loop fp32->f16 k-transpose (Bh) had 16-way read AND write
// conflicts (768-byte lane strides == 0 mod 128 B).
//
// Round-3 fix (ws-gated): if ws_size >= 52 MB, a prep kernel materializes the
// bases as f16 [a][b][k] (k fastest) ONCE; consumers then stage Bh with
// verbatim conflict-free b128 copies, and Wt uses conflict-free padded
// strides (f-stride 40 halfs, l-stride 648 halfs; all b128 accesses 16-B
// aligned, 8 classes x 8 lanes = zero-conflict). If ws is small, fall back
// to the round-2 kernels (proven pass).
// ---------------------------------------------------------------------------

typedef _Float16 half8 __attribute__((ext_vector_type(8)));
typedef _Float16 half4 __attribute__((ext_vector_type(4)));
typedef float    f32x4 __attribute__((ext_vector_type(4)));

#define MFMA_F16 __builtin_amdgcn_mfma_f32_16x16x32_f16

// fast-path workspace layout (bytes)
static constexpr size_t OFF_P1 = 0;
static constexpr size_t OFF_P2 = 16777216;
static constexpr size_t OFF_P3 = 33554432;
static constexpr size_t OFF_HPF = 50331648;
static constexpr size_t WS_FAST = OFF_HPF + 4194304;   // 54,525,952

// ---------------------------------------------------------------------------
// prep: (K, A, Bd) fp32  ->  [a][b][k] f16   (k contiguous, 32 B per (a,b))
// z = 0: gate (A=512,Bd=1024)  z = 1: up  z = 2: down (A=1024,Bd=512)
// ---------------------------------------------------------------------------
__global__ __launch_bounds__(256) void prep_basis_all(
    const float* __restrict__ wg, const float* __restrict__ wu,
    const float* __restrict__ wd,
    _Float16* __restrict__ P1, _Float16* __restrict__ P2,
    _Float16* __restrict__ P3)
{
    int z = blockIdx.y;
    const float* src = (z == 0) ? wg : (z == 1) ? wu : wd;
    _Float16*    dst = (z == 0) ? P1 : (z == 1) ? P2 : P3;
    int A  = (z == 2) ? 1024 : 512;
    int Bd = (z == 2) ? 512 : 1024;
    int nb = Bd >> 6;
    int a0 = (blockIdx.x / nb) * 4;
    int b0 = (blockIdx.x % nb) * 64;

    __shared__ __align__(16) float S[16 * 257];
    int tid = threadIdx.x;
#pragma unroll
    for (int k = 0; k < 16; ++k)
        S[k * 257 + tid] =
            src[(size_t)k * A * Bd + (size_t)(a0 + (tid >> 6)) * Bd + b0 + (tid & 63)];
    __syncthreads();

    int a = tid >> 6, b = tid & 63;
    const float* col = &S[tid];
    half8 v0, v1;
#pragma unroll
    for (int k = 0; k < 8; ++k) v0[k] = (_Float16)col[k * 257];
#pragma unroll
    for (int k = 0; k < 8; ++k) v1[k] = (_Float16)col[(k + 8) * 257];
    _Float16* out = dst + ((size_t)(a0 + a) * Bd + (b0 + b)) * 16;
    *(half8*)out       = v0;
    *(half8*)(out + 8) = v1;
}

// ---------------------------------------------------------------------------
// up_fast: 512 blocks = 8 l-groups x 64 f-tiles, 256 threads.
// LDS: Xt 20480 + Bh 16896 + Wt 20736 + CN 2048 = 60160 B.
// ---------------------------------------------------------------------------
__global__ __launch_bounds__(256) void up_fast(
    const _Float16* __restrict__ P1, const _Float16* __restrict__ P2,
    const float* __restrict__ x,
    const float* __restrict__ tc1, const float* __restrict__ tc2,
    const float* __restrict__ usp, const float* __restrict__ vsp,
    _Float16* __restrict__ Hp)
{
    int lg = blockIdx.x >> 6;
    int f0 = (blockIdx.x & 63) * 16;
    int tid = threadIdx.x;
    int w = tid >> 6, lane = tid & 63;
    int n = lane & 15, kc = lane >> 4;

    __shared__ __align__(16) _Float16 Xt[256 * 40];   // [l*16+b][d32 pad40]
    __shared__ __align__(16) _Float16 Bh[32 * 264];   // [dd][f*16+k] (pad 8)
    __shared__ __align__(16) _Float16 Wt[16 * 648];   // [l][f*40+d32] pads
    __shared__ float CN[2 * 256];

    if (tid < 32) {
        int s = tid >> 4, ll = tid & 15;
        const float* row = (s ? tc2 : tc1) + (size_t)(lg * 16 + ll) * 16;
        float e[16], m = -1e30f, sum = 0.f;
#pragma unroll
        for (int k = 0; k < 16; ++k) m = fmaxf(m, row[k]);
#pragma unroll
        for (int k = 0; k < 16; ++k) { e[k] = __expf(row[k] - m); sum += e[k]; }
        float r = 1.f / sum;
#pragma unroll
        for (int k = 0; k < 16; ++k) CN[s * 256 + ll * 16 + k] = e[k] * r;
    }
    __syncthreads();

    half8 cf1 = { 0, 0, 0, 0, 0, 0, 0, 0 };
    half8 cf2 = { 0, 0, 0, 0, 0, 0, 0, 0 };
    if (kc < 2) {
#pragma unroll
        for (int j = 0; j < 8; ++j) {
            cf1[j] = (_Float16)CN[0 * 256 + n * 16 + kc * 8 + j];
            cf2[j] = (_Float16)CN[1 * 256 + n * 16 + kc * 8 + j];
        }
    }

    f32x4 zf = { 0.f, 0.f, 0.f, 0.f };
    f32x4 aU[4], aV[4];
#pragma unroll
    for (int i = 0; i < 4; ++i) { aU[i] = zf; aV[i] = zf; }
    float nsqU[4] = { 0.f, 0.f, 0.f, 0.f };
    float nsqV[4] = { 0.f, 0.f, 0.f, 0.f };

    for (int it = 0; it < 16; ++it) {
        int d0 = it * 32;
        // stage x chunk -> Xt f16
#pragma unroll
        for (int p = 0; p < 8; ++p) {
            int r = p * 32 + (tid >> 3);
            int fj = tid & 7;
            int ll = r >> 4, b = r & 15;
            f32x4 v = *(const f32x4*)(
                x + ((size_t)(b * 128 + lg * 16 + ll) * 512 + d0 + fj * 4));
            half4 h = { (_Float16)v[0], (_Float16)v[1],
                        (_Float16)v[2], (_Float16)v[3] };
            *(half4*)(&Xt[r * 40 + fj * 4]) = h;
        }
        // stage Bh (gate) — verbatim b128 copy, conflict-free
#pragma unroll
        for (int i = 0; i < 4; ++i) {
            int u = i * 256 + tid;
            int dd = u >> 5, seg = u & 31;
            *(half8*)(&Bh[dd * 264 + seg * 8]) = *(const half8*)(
                P1 + ((size_t)(d0 + dd) * 1024 + f0) * 16 + seg * 8);
        }
        __syncthreads();
        // mix W1 -> Wt (+ nsqU)
#pragma unroll
        for (int fl = 0; fl < 4; ++fl) {
            int f_l = w * 4 + fl;
#pragma unroll
            for (int dg = 0; dg < 2; ++dg) {
                half8 a = { 0, 0, 0, 0, 0, 0, 0, 0 };
                if (kc < 2)
                    a = *(const half8*)(&Bh[(dg * 16 + n) * 264 + f_l * 16 + kc * 8]);
                f32x4 cw = MFMA_F16(a, cf1, zf, 0, 0, 0);
                nsqU[fl] += cw[0] * cw[0] + cw[1] * cw[1]
                          + cw[2] * cw[2] + cw[3] * cw[3];
                half4 h4 = { (_Float16)cw[0], (_Float16)cw[1],
                             (_Float16)cw[2], (_Float16)cw[3] };
                *(half4*)(&Wt[n * 648 + f_l * 40 + dg * 16 + kc * 4]) = h4;
            }
        }
        __syncthreads();
        // consume U ; stage Bh (up)
#pragma unroll
        for (int li = 0; li < 4; ++li) {
            int l = w * 4 + li;
            half8 xf = *(const half8*)(&Xt[(l * 16 + n) * 40 + kc * 8]);
            half8 wf = *(const half8*)(&Wt[l * 648 + n * 40 + kc * 8]);
            aU[li] = MFMA_F16(xf, wf, aU[li], 0, 0, 0);
        }
#pragma unroll
        for (int i = 0; i < 4; ++i) {
            int u = i * 256 + tid;
            int dd = u >> 5, seg = u & 31;
            *(half8*)(&Bh[dd * 264 + seg * 8]) = *(const half8*)(
                P2 + ((size_t)(d0 + dd) * 1024 + f0) * 16 + seg * 8);
        }
        __syncthreads();
        // mix W2 -> Wt (+ nsqV)
#pragma unroll
        for (int fl = 0; fl < 4; ++fl) {
            int f_l = w * 4 + fl;
#pragma unroll
            for (int dg = 0; dg < 2; ++dg) {
                half8 a = { 0, 0, 0, 0, 0, 0, 0, 0 };
                if (kc < 2)
                    a = *(const half8*)(&Bh[(dg * 16 + n) * 264 + f_l * 16 + kc * 8]);
                f32x4 cw = MFMA_F16(a, cf2, zf, 0, 0, 0);
                nsqV[fl] += cw[0] * cw[0] + cw[1] * cw[1]
                          + cw[2] * cw[2] + cw[3] * cw[3];
                half4 h4 = { (_Float16)cw[0], (_Float16)cw[1],
                             (_Float16)cw[2], (_Float16)cw[3] };
                *(half4*)(&Wt[n * 648 + f_l * 40 + dg * 16 + kc * 4]) = h4;
            }
        }
        __syncthreads();
        // consume V
#pragma unroll
        for (int li = 0; li < 4; ++li) {
            int l = w * 4 + li;
            half8 xf = *(const half8*)(&Xt[(l * 16 + n) * 40 + kc * 8]);
            half8 wf = *(const half8*)(&Wt[l * 648 + n * 40 + kc * 8]);
            aV[li] = MFMA_F16(xf, wf, aV[li], 0, 0, 0);
        }
        __syncthreads();
    }

#pragma unroll
    for (int fl = 0; fl < 4; ++fl) {
        float vU = nsqU[fl], vV = nsqV[fl];
        vU += __shfl_xor(vU, 16); vU += __shfl_xor(vU, 32);
        vV += __shfl_xor(vV, 16); vV += __shfl_xor(vV, 32);
        if (kc == 0) {
            CN[0 * 256 + n * 16 + w * 4 + fl] = vU;
            CN[1 * 256 + n * 16 + w * 4 + fl] = vV;
        }
    }
    __syncthreads();

    int f = f0 + n;
    float usv = fabsf(usp[f]);
    float vsv = fabsf(vsp[f]) * 22.627416997969522f;
#pragma unroll
    for (int li = 0; li < 4; ++li) {
        int lgl = lg * 16 + w * 4 + li;
        float r1 = 1.f / fmaxf(sqrtf(CN[0 * 256 + (w * 4 + li) * 16 + n]), 1e-12f);
        float r2 = 1.f / fmaxf(sqrtf(CN[1 * 256 + (w * 4 + li) * 16 + n]), 1e-12f);
#pragma unroll
        for (int i = 0; i < 4; ++i) {
            float u = aU[li][i] * r1;
            float v = aV[li][i] * r2;
            float zz = vsv * v;
            float sil = zz / (1.f + __expf(-zz));
            float h = sil * (usv * u);
            Hp[((size_t)lgl * 16 + kc * 4 + i) * 1024 + f] = (_Float16)h;
        }
    }
}

// ---------------------------------------------------------------------------
// down_fast: 256 blocks = 8 l-groups x 32 d-tiles, 256 threads.
// ---------------------------------------------------------------------------
__global__ __launch_bounds__(256) void down_fast(
    const _Float16* __restrict__ P3, const float* __restrict__ tc3,
    const _Float16* __restrict__ Hp, float* __restrict__ out)
{
    int lg = blockIdx.x >> 5;
    int d0 = (blockIdx.x & 31) * 16;
    int tid = threadIdx.x;
    int w = tid >> 6, lane = tid & 63;
    int n = lane & 15, kc = lane >> 4;

    __shared__ __align__(16) _Float16 Ht[256 * 40];   // [l*16+b][f32 pad40]
    __shared__ __align__(16) _Float16 Bh[32 * 264];   // [ff][d*16+k]
    __shared__ __align__(16) _Float16 Wt[16 * 648];   // [l][d*40+f32]
    __shared__ float CN[256];

    if (tid < 16) {
        const float* row = tc3 + (size_t)(lg * 16 + tid) * 16;
        float e[16], m = -1e30f, sum = 0.f;
#pragma unroll
        for (int k = 0; k < 16; ++k) m = fmaxf(m, row[k]);
#pragma unroll
        for (int k = 0; k < 16; ++k) { e[k] = __expf(row[k] - m); sum += e[k]; }
        float r = 1.f / sum;
#pragma unroll
        for (int k = 0; k < 16; ++k) CN[tid * 16 + k] = e[k] * r;
    }
    __syncthreads();

    half8 cf3 = { 0, 0, 0, 0, 0, 0, 0, 0 };
    if (kc < 2) {
#pragma unroll
        for (int j = 0; j < 8; ++j)
            cf3[j] = (_Float16)CN[n * 16 + kc * 8 + j];
    }

    f32x4 zf = { 0.f, 0.f, 0.f, 0.f };
    f32x4 aO[4];
#pragma unroll
    for (int i = 0; i < 4; ++i) aO[i] = zf;
    float nsqD[4] = { 0.f, 0.f, 0.f, 0.f };

    for (int it = 0; it < 32; ++it) {
        int f0 = it * 32;
#pragma unroll
        for (int p = 0; p < 8; ++p) {
            int r = p * 32 + (tid >> 3);
            int hj = tid & 7;
            int ll = r >> 4, b = r & 15;
            half4 v = *(const half4*)(
                Hp + ((size_t)(lg * 16 + ll) * 16 + b) * 1024 + f0 + hj * 4);
            *(half4*)(&Ht[r * 40 + hj * 4]) = v;
        }
#pragma unroll
        for (int i = 0; i < 4; ++i) {
            int u = i * 256 + tid;
            int ff = u >> 5, seg = u & 31;
            *(half8*)(&Bh[ff * 264 + seg * 8]) = *(const half8*)(
                P3 + ((size_t)(f0 + ff) * 512 + d0) * 16 + seg * 8);
        }
        __syncthreads();
#pragma unroll
        for (int dl = 0; dl < 4; ++dl) {
            int d_l = w * 4 + dl;
#pragma unroll
            for (int fg = 0; fg < 2; ++fg) {
                half8 a = { 0, 0, 0, 0, 0, 0, 0, 0 };
                if (kc < 2)
                    a = *(const half8*)(&Bh[(fg * 16 + n) * 264 + d_l * 16 + kc * 8]);
                f32x4 cw = MFMA_F16(a, cf3, zf, 0, 0, 0);
                nsqD[dl] += cw[0] * cw[0] + cw[1] * cw[1]
                          + cw[2] * cw[2] + cw[3] * cw[3];
                half4 h4 = { (_Float16)cw[0], (_Float16)cw[1],
                             (_Float16)cw[2], (_Float16)cw[3] };
                *(half4*)(&Wt[n * 648 + d_l * 40 + fg * 16 + kc * 4]) = h4;
            }
        }
        __syncthreads();
#pragma unroll
        for (int li = 0; li < 4; ++li) {
            int l = w * 4 + li;
            half8 hf = *(const half8*)(&Ht[(l * 16 + n) * 40 + kc * 8]);
            half8 wf = *(const half8*)(&Wt[l * 648 + n * 40 + kc * 8]);
            aO[li] = MFMA_F16(hf, wf, aO[li], 0, 0, 0);
        }
        __syncthreads();
    }

#pragma unroll
    for (int dl = 0; dl < 4; ++dl) {
        float v = nsqD[dl];
        v += __shfl_xor(v, 16); v += __shfl_xor(v, 32);
        if (kc == 0) CN[n * 16 + w * 4 + dl] = v;
    }
    __syncthreads();

#pragma unroll
    for (int li = 0; li < 4; ++li) {
        int lgl = lg * 16 + w * 4 + li;
        float r3 = 1.f / fmaxf(sqrtf(CN[(w * 4 + li) * 16 + n]), 1e-12f);
#pragma unroll
        for (int i = 0; i < 4; ++i)
            out[((size_t)(kc * 4 + i) * 128 + lgl) * 512 + d0 + n] = aO[li][i] * r3;
    }
}

// ===========================================================================
// SLOW FALLBACK (round-2 kernels, proven) — used when ws_size < WS_FAST
// ===========================================================================
__global__ __launch_bounds__(256) void up_kernel(
    const float* __restrict__ x,
    const float* __restrict__ wg, const float* __restrict__ wu,
    const float* __restrict__ tc1, const float* __restrict__ tc2,
    const float* __restrict__ usp, const float* __restrict__ vsp,
    _Float16* __restrict__ Hp)
{
    int lg = blockIdx.x >> 6;
    int f0 = (blockIdx.x & 63) * 16;
    int tid = threadIdx.x;
    int w = tid >> 6, lane = tid & 63;
    int n = lane & 15, kc = lane >> 4;

    __shared__ __align__(16) _Float16 Xt[256 * 40];
    __shared__ __align__(16) _Float16 Bh[32 * 16 * 24];
    __shared__ __align__(16) _Float16 Wt[16 * 528];
    __shared__ float CN[2 * 16 * 16];

    if (tid < 32) {
        int s = tid >> 4, ll = tid & 15;
        const float* row = (s ? tc2 : tc1) + (size_t)(lg * 16 + ll) * 16;
        float e[16], m = -1e30f, sum = 0.f;
#pragma unroll
        for (int k = 0; k < 16; ++k) m = fmaxf(m, row[k]);
#pragma unroll
        for (int k = 0; k < 16; ++k) { e[k] = __expf(row[k] - m); sum += e[k]; }
        float r = 1.f / sum;
#pragma unroll
        for (int k = 0; k < 16; ++k) CN[s * 256 + ll * 16 + k] = e[k] * r;
    }
    __syncthreads();

    half8 cf1 = { 0, 0, 0, 0, 0, 0, 0, 0 };
    half8 cf2 = { 0, 0, 0, 0, 0, 0, 0, 0 };
    if (kc < 2) {
#pragma unroll
        for (int j = 0; j < 8; ++j) {
            cf1[j] = (_Float16)CN[0 * 256 + n * 16 + kc * 8 + j];
            cf2[j] = (_Float16)CN[1 * 256 + n * 16 + kc * 8 + j];
        }
    }

    f32x4 zf = { 0.f, 0.f, 0.f, 0.f };
    f32x4 aU[4], aV[4];
#pragma unroll
    for (int i = 0; i < 4; ++i) { aU[i] = zf; aV[i] = zf; }
    float nsqU[4] = { 0.f, 0.f, 0.f, 0.f };
    float nsqV[4] = { 0.f, 0.f, 0.f, 0.f };

    for (int it = 0; it < 16; ++it) {
        int d0 = it * 32;
#pragma unroll
        for (int p = 0; p < 8; ++p) {
            int r = p * 32 + (tid >> 3);
            int fj = tid & 7;
            int ll = r >> 4, b = r & 15;
            f32x4 v = *(const f32x4*)(
                x + ((size_t)(b * 128 + lg * 16 + ll) * 512 + d0 + fj * 4));
            half4 h = { (_Float16)v[0], (_Float16)v[1],
                        (_Float16)v[2], (_Float16)v[3] };
            *(half4*)(&Xt[r * 40 + fj * 4]) = h;
        }
#pragma unroll
        for (int p = 0; p < 8; ++p) {
            int idx = p * 256 + tid;
            int q = idx & 3, dd = (idx >> 2) & 31, k = idx >> 7;
            f32x4 v = *(const f32x4*)(
                wg + ((size_t)k * 512 + d0 + dd) * 1024 + f0 + q * 4);
#pragma unroll
            for (int j = 0; j < 4; ++j)
                Bh[(dd * 16 + q * 4 + j) * 24 + k] = (_Float16)v[j];
        }
        __syncthreads();
#pragma unroll
        for (int fl = 0; fl < 4; ++fl) {
            int f_l = w * 4 + fl;
#pragma unroll
            for (int dg = 0; dg < 2; ++dg) {
                half8 a = { 0, 0, 0, 0, 0, 0, 0, 0 };
                if (kc < 2)
                    a = *(const half8*)(&Bh[((dg * 16 + n) * 16 + f_l) * 24 + kc * 8]);
                f32x4 cw = MFMA_F16(a, cf1, zf, 0, 0, 0);
                nsqU[fl] += cw[0] * cw[0] + cw[1] * cw[1]
                          + cw[2] * cw[2] + cw[3] * cw[3];
                half4 h4 = { (_Float16)cw[0], (_Float16)cw[1],
                             (_Float16)cw[2], (_Float16)cw[3] };
                *(half4*)(&Wt[n * 528 + f_l * 32 + dg * 16 + kc * 4]) = h4;
            }
        }
        __syncthreads();
#pragma unroll
        for (int li = 0; li < 4; ++li) {
            int l = w * 4 + li;
            half8 xf = *(const half8*)(&Xt[(l * 16 + n) * 40 + kc * 8]);
            half8 wf = *(const half8*)(&Wt[l * 528 + n * 32 + kc * 8]);
            aU[li] = MFMA_F16(xf, wf, aU[li], 0, 0, 0);
        }
#pragma unroll
        for (int p = 0; p < 8; ++p) {
            int idx = p * 256 + tid;
            int q = idx & 3, dd = (idx >> 2) & 31, k = idx >> 7;
            f32x4 v = *(const f32x4*)(
                wu + ((size_t)k * 512 + d0 + dd) * 1024 + f0 + q * 4);
#pragma unroll
            for (int j = 0; j < 4; ++j)
                Bh[(dd * 16 + q * 4 + j) * 24 + k] = (_Float16)v[j];
        }
        __syncthreads();
#pragma unroll
        for (int fl = 0; fl < 4; ++fl) {
            int f_l = w * 4 + fl;
#pragma unroll
            for (int dg = 0; dg < 2; ++dg) {
                half8 a = { 0, 0, 0, 0, 0, 0, 0, 0 };
                if (kc < 2)
                    a = *(const half8*)(&Bh[((dg * 16 + n) * 16 + f_l) * 24 + kc * 8]);
                f32x4 cw = MFMA_F16(a, cf2, zf, 0, 0, 0);
                nsqV[fl] += cw[0] * cw[0] + cw[1] * cw[1]
                          + cw[2] * cw[2] + cw[3] * cw[3];
                half4 h4 = { (_Float16)cw[0], (_Float16)cw[1],
                             (_Float16)cw[2], (_Float16)cw[3] };
                *(half4*)(&Wt[n * 528 + f_l * 32 + dg * 16 + kc * 4]) = h4;
            }
        }
        __syncthreads();
#pragma unroll
        for (int li = 0; li < 4; ++li) {
            int l = w * 4 + li;
            half8 xf = *(const half8*)(&Xt[(l * 16 + n) * 40 + kc * 8]);
            half8 wf = *(const half8*)(&Wt[l * 528 + n * 32 + kc * 8]);
            aV[li] = MFMA_F16(xf, wf, aV[li], 0, 0, 0);
        }
        __syncthreads();
    }

#pragma unroll
    for (int fl = 0; fl < 4; ++fl) {
        float vU = nsqU[fl], vV = nsqV[fl];
        vU += __shfl_xor(vU, 16); vU += __shfl_xor(vU, 32);
        vV += __shfl_xor(vV, 16); vV += __shfl_xor(vV, 32);
        if (kc == 0) {
            CN[0 * 256 + n * 16 + w * 4 + fl] = vU;
            CN[1 * 256 + n * 16 + w * 4 + fl] = vV;
        }
    }
    __syncthreads();

    int f = f0 + n;
    float usv = fabsf(usp[f]);
    float vsv = fabsf(vsp[f]) * 22.627416997969522f;
#pragma unroll
    for (int li = 0; li < 4; ++li) {
        int lgl = lg * 16 + w * 4 + li;
        float r1 = 1.f / fmaxf(sqrtf(CN[0 * 256 + (w * 4 + li) * 16 + n]), 1e-12f);
        float r2 = 1.f / fmaxf(sqrtf(CN[1 * 256 + (w * 4 + li) * 16 + n]), 1e-12f);
#pragma unroll
        for (int i = 0; i < 4; ++i) {
            float u = aU[li][i] * r1;
            float v = aV[li][i] * r2;
            float zz = vsv * v;
            float sil = zz / (1.f + __expf(-zz));
            float h = sil * (usv * u);
            Hp[((size_t)lgl * 16 + kc * 4 + i) * 1024 + f] = (_Float16)h;
        }
    }
}

__global__ __launch_bounds__(256) void down_kernel(
    const float* __restrict__ wd, const float* __restrict__ tc3,
    const _Float16* __restrict__ Hp, float* __restrict__ out)
{
    int lg = blockIdx.x >> 5;
    int d0 = (blockIdx.x & 31) * 16;
    int tid = threadIdx.x;
    int w = tid >> 6, lane = tid & 63;
    int n = lane & 15, kc = lane >> 4;

    __shared__ __align__(16) _Float16 Ht[256 * 40];
    __shared__ __align__(16) _Float16 Bh[32 * 16 * 24];
    __shared__ __align__(16) _Float16 Wt[16 * 528];
    __shared__ float CN[16 * 16];

    if (tid < 16) {
        const float* row = tc3 + (size_t)(lg * 16 + tid) * 16;
        float e[16], m = -1e30f, sum = 0.f;
#pragma unroll
        for (int k = 0; k < 16; ++k) m = fmaxf(m, row[k]);
#pragma unroll
        for (int k = 0; k < 16; ++k) { e[k] = __expf(row[k] - m); sum += e[k]; }
        float r = 1.f / sum;
#pragma unroll
        for (int k = 0; k < 16; ++k) CN[tid * 16 + k] = e[k] * r;
    }
    __syncthreads();

    half8 cf3 = { 0, 0, 0, 0, 0, 0, 0, 0 };
    if (kc < 2) {
#pragma unroll
        for (int j = 0; j < 8; ++j)
            cf3[j] = (_Float16)CN[n * 16 + kc * 8 + j];
    }

    f32x4 zf = { 0.f, 0.f, 0.f, 0.f };
    f32x4 aO[4];
#pragma unroll
    for (int i = 0; i < 4; ++i) aO[i] = zf;
    float nsqD[4] = { 0.f, 0.f, 0.f, 0.f };

    for (int it = 0; it < 32; ++it) {
        int f0 = it * 32;
#pragma unroll
        for (int p = 0; p < 8; ++p) {
            int r = p * 32 + (tid >> 3);
            int hj = tid & 7;
            int ll = r >> 4, b = r & 15;
            half4 v = *(const half4*)(
                Hp + ((size_t)(lg * 16 + ll) * 16 + b) * 1024 + f0 + hj * 4);
            *(half4*)(&Ht[r * 40 + hj * 4]) = v;
        }
#pragma unroll
        for (int p = 0; p < 8; ++p) {
            int idx = p * 256 + tid;
            int q = idx & 3, ff = (idx >> 2) & 31, k = idx >> 7;
            f32x4 v = *(const f32x4*)(
                wd + ((size_t)k * 1024 + f0 + ff) * 512 + d0 + q * 4);
#pragma unroll
            for (int j = 0; j < 4; ++j)
                Bh[(ff * 16 + q * 4 + j) * 24 + k] = (_Float16)v[j];
        }
        __syncthreads();
#pragma unroll
        for (int dl = 0; dl < 4; ++dl) {
            int d_l = w * 4 + dl;
#pragma unroll
            for (int fg = 0; fg < 2; ++fg) {
                half8 a = { 0, 0, 0, 0, 0, 0, 0, 0 };
                if (kc < 2)
                    a = *(const half8*)(&Bh[((fg * 16 + n) * 16 + d_l) * 24 + kc * 8]);
                f32x4 cw = MFMA_F16(a, cf3, zf, 0, 0, 0);
                nsqD[dl] += cw[0] * cw[0] + cw[1] * cw[1]
                          + cw[2] * cw[2] + cw[3] * cw[3];
                half4 h4 = { (_Float16)cw[0], (_Float16)cw[1],
                             (_Float16)cw[2], (_Float16)cw[3] };
                *(half4*)(&Wt[n * 528 + d_l * 32 + fg * 16 + kc * 4]) = h4;
            }
        }
        __syncthreads();
#pragma unroll
        for (int li = 0; li < 4; ++li) {
            int l = w * 4 + li;
            half8 hf = *(const half8*)(&Ht[(l * 16 + n) * 40 + kc * 8]);
            half8 wf = *(const half8*)(&Wt[l * 528 + n * 32 + kc * 8]);
            aO[li] = MFMA_F16(hf, wf, aO[li], 0, 0, 0);
        }
        __syncthreads();
    }

#pragma unroll
    for (int dl = 0; dl < 4; ++dl) {
        float v = nsqD[dl];
        v += __shfl_xor(v, 16); v += __shfl_xor(v, 32);
        if (kc == 0) CN[n * 16 + w * 4 + dl] = v;
    }
    __syncthreads();

#pragma unroll
    for (int li = 0; li < 4; ++li) {
        int lgl = lg * 16 + w * 4 + li;
        float r3 = 1.f / fmaxf(sqrtf(CN[(w * 4 + li) * 16 + n]), 1e-12f);
#pragma unroll
        for (int i = 0; i < 4; ++i)
            out[((size_t)(kc * 4 + i) * 128 + lgl) * 512 + d0 + n] = aO[li][i] * r3;
    }
}

// ---------------------------------------------------------------------------
__global__ __launch_bounds__(128) void final_kernel(float* __restrict__ out)
{
    int rid = blockIdx.x;
    int t = threadIdx.x;
    f32x4 y = *(const f32x4*)(out + (size_t)rid * 512 + t * 4);
    float s = y[0] * y[0] + y[1] * y[1] + y[2] * y[2] + y[3] * y[3];
#pragma unroll
    for (int off = 32; off > 0; off >>= 1) s += __shfl_down(s, off);
    __shared__ float sred[2];
    if ((t & 63) == 0) sred[t >> 6] = s;
    __syncthreads();
    float rr = 1.f / fmaxf(sqrtf(sred[0] + sred[1]), 1e-12f);
    f32x4 o = { y[0] * rr, y[1] * rr, y[2] * rr, y[3] * rr };
    *(f32x4*)(out + (size_t)rid * 512 + t * 4) = o;
}

// ---------------------------------------------------------------------------
extern "C" void kernel_launch(void* const* d_in, const int* in_sizes, int n_in,
                              void* d_out, int out_size, void* d_ws, size_t ws_size,
                              hipStream_t stream)
{
    (void)in_sizes; (void)n_in; (void)out_size;
    const float* x   = (const float*)d_in[0];
    const float* wg  = (const float*)d_in[1];
    const float* wu  = (const float*)d_in[2];
    const float* wd  = (const float*)d_in[3];
    const float* tc1 = (const float*)d_in[4];
    const float* tc2 = (const float*)d_in[5];
    const float* tc3 = (const float*)d_in[6];
    const float* usp = (const float*)d_in[7];
    const float* vsp = (const float*)d_in[8];
    float* outp = (float*)d_out;
    char* ws = (char*)d_ws;

    if (ws_size >= WS_FAST) {
        _Float16* P1 = (_Float16*)(ws + OFF_P1);
        _Float16* P2 = (_Float16*)(ws + OFF_P2);
        _Float16* P3 = (_Float16*)(ws + OFF_P3);
        _Float16* Hp = (_Float16*)(ws + OFF_HPF);
        prep_basis_all<<<dim3(2048, 3), dim3(256), 0, stream>>>(wg, wu, wd,
                                                                P1, P2, P3);
        up_fast<<<dim3(512), dim3(256), 0, stream>>>(P1, P2, x, tc1, tc2,
                                                     usp, vsp, Hp);
        down_fast<<<dim3(256), dim3(256), 0, stream>>>(P3, tc3, Hp, outp);
        final_kernel<<<dim3(2048), dim3(128), 0, stream>>>(outp);
    } else {
        _Float16* Hp = (_Float16*)ws;          // 4 MB only
        up_kernel<<<dim3(512), dim3(256), 0, stream>>>(x, wg, wu, tc1, tc2,
                                                       usp, vsp, Hp);
        down_kernel<<<dim3(256), dim3(256), 0, stream>>>(wd, tc3, Hp, outp);
        final_kernel<<<dim3(2048), dim3(128), 0, stream>>>(outp);
    }
}

// Round 4
// 238.736 us; speedup vs baseline: 1.7774x; 1.0918x over previous
//
#include <hip/hip_runtime.h>
#include <hip/hip_bf16.h>
#include <cmath>

// ---------------------------------------------------------------------------
// NPerTokenSwishGLU_Basis — fused f16-MFMA implementation (gfx950), round 4.
//
// Round-3 post-mortem: conflicts fixed (8e7 -> 6.6e6) but up_fast is
// barrier/latency bound (MfmaUtil 7%, VALUBusy 28%, HBM 7%, occ 19%).
// Round-4: 2-phase software pipeline in both MFMA kernels:
//   Phase A: consume(i-1) from Wt  +  stage Bh(i)          | barrier
//   Phase B: mix(i) -> Wt  +  prefetch x/h frags global->reg | barrier
// Xt/Ht LDS staging deleted (A-frags read directly from L2-resident x / Hp
// with one-iteration prefetch distance). Down split-f x2 (grid 512) writing
// partial sums + partial col-norms into ws (overlaying dead P1/P2 region);
// final_kernel combines, applies rn3 and the row L2-norm.
// ws use: P1/P2/P3 48 MB + Hp 4 MB = 52 MB (ws_size >= 54.5 MB proven R3).
// ---------------------------------------------------------------------------

typedef _Float16 half8 __attribute__((ext_vector_type(8)));
typedef _Float16 half4 __attribute__((ext_vector_type(4)));
typedef float    f32x4 __attribute__((ext_vector_type(4)));

#define MFMA_F16 __builtin_amdgcn_mfma_f32_16x16x32_f16

static constexpr size_t OFF_P1 = 0;            // 16 MB (up); Rp overlay (down)
static constexpr size_t OFF_P2 = 16777216;     // 16 MB (up); Np overlay (down)
static constexpr size_t OFF_P3 = 33554432;     // 16 MB
static constexpr size_t OFF_HP = 50331648;     // 4 MB
static constexpr size_t WS_FAST = OFF_HP + 4194304;   // 54,525,952

// ---------------------------------------------------------------------------
// prep: (K, A, Bd) fp32  ->  [a][b][k] f16   (k contiguous, 32 B per (a,b))
// ---------------------------------------------------------------------------
__global__ __launch_bounds__(256) void prep_basis_all(
    const float* __restrict__ wg, const float* __restrict__ wu,
    const float* __restrict__ wd,
    _Float16* __restrict__ P1, _Float16* __restrict__ P2,
    _Float16* __restrict__ P3)
{
    int z = blockIdx.y;
    const float* src = (z == 0) ? wg : (z == 1) ? wu : wd;
    _Float16*    dst = (z == 0) ? P1 : (z == 1) ? P2 : P3;
    int A  = (z == 2) ? 1024 : 512;
    int Bd = (z == 2) ? 512 : 1024;
    int nb = Bd >> 6;
    int a0 = (blockIdx.x / nb) * 4;
    int b0 = (blockIdx.x % nb) * 64;

    __shared__ __align__(16) float S[16 * 257];
    int tid = threadIdx.x;
#pragma unroll
    for (int k = 0; k < 16; ++k)
        S[k * 257 + tid] =
            src[(size_t)k * A * Bd + (size_t)(a0 + (tid >> 6)) * Bd + b0 + (tid & 63)];
    __syncthreads();

    int a = tid >> 6, b = tid & 63;
    const float* col = &S[tid];
    half8 v0, v1;
#pragma unroll
    for (int k = 0; k < 8; ++k) v0[k] = (_Float16)col[k * 257];
#pragma unroll
    for (int k = 0; k < 8; ++k) v1[k] = (_Float16)col[(k + 8) * 257];
    _Float16* out = dst + ((size_t)(a0 + a) * Bd + (b0 + b)) * 16;
    *(half8*)out       = v0;
    *(half8*)(out + 8) = v1;
}

// ---------------------------------------------------------------------------
// up_fast: 512 blocks = 8 l-groups x 64 f-tiles, 256 threads.
// LDS: Bh 33792 + Wt 41472 + CN 2048 = 77312 B  -> 2 blocks/CU.
// ---------------------------------------------------------------------------
__global__ __launch_bounds__(256) void up_fast(
    const _Float16* __restrict__ P1, const _Float16* __restrict__ P2,
    const float* __restrict__ x,
    const float* __restrict__ tc1, const float* __restrict__ tc2,
    const float* __restrict__ usp, const float* __restrict__ vsp,
    _Float16* __restrict__ Hp)
{
    int lg = blockIdx.x >> 6;
    int f0 = (blockIdx.x & 63) * 16;
    int tid = threadIdx.x;
    int w = tid >> 6, lane = tid & 63;
    int n = lane & 15, kc = lane >> 4;

    __shared__ __align__(16) _Float16 Bh[2][32 * 264]; // [mat][dd][f*16+k]
    __shared__ __align__(16) _Float16 Wt[2][16 * 648]; // [mat][l][f*40+d32]
    __shared__ float CN[2 * 256];

    if (tid < 32) {
        int s = tid >> 4, ll = tid & 15;
        const float* row = (s ? tc2 : tc1) + (size_t)(lg * 16 + ll) * 16;
        float e[16], m = -1e30f, sum = 0.f;
#pragma unroll
        for (int k = 0; k < 16; ++k) m = fmaxf(m, row[k]);
#pragma unroll
        for (int k = 0; k < 16; ++k) { e[k] = __expf(row[k] - m); sum += e[k]; }
        float r = 1.f / sum;
#pragma unroll
        for (int k = 0; k < 16; ++k) CN[s * 256 + ll * 16 + k] = e[k] * r;
    }
    __syncthreads();

    half8 cf1 = { 0, 0, 0, 0, 0, 0, 0, 0 };
    half8 cf2 = { 0, 0, 0, 0, 0, 0, 0, 0 };
    if (kc < 2) {
#pragma unroll
        for (int j = 0; j < 8; ++j) {
            cf1[j] = (_Float16)CN[0 * 256 + n * 16 + kc * 8 + j];
            cf2[j] = (_Float16)CN[1 * 256 + n * 16 + kc * 8 + j];
        }
    }

    f32x4 zf = { 0.f, 0.f, 0.f, 0.f };
    f32x4 aU[4], aV[4];
#pragma unroll
    for (int i = 0; i < 4; ++i) { aU[i] = zf; aV[i] = zf; }
    float nsqU[4] = { 0.f, 0.f, 0.f, 0.f };
    float nsqV[4] = { 0.f, 0.f, 0.f, 0.f };
    half8 xf[4];

    for (int it = 0; it < 16; ++it) {
        int d0 = it * 32;
        // ---- Phase A: consume(it-1) + stage Bh(it) ----
        if (it > 0) {
#pragma unroll
            for (int li = 0; li < 4; ++li) {
                int l = w * 4 + li;
                half8 wU = *(const half8*)(&Wt[0][l * 648 + n * 40 + kc * 8]);
                half8 wV = *(const half8*)(&Wt[1][l * 648 + n * 40 + kc * 8]);
                aU[li] = MFMA_F16(xf[li], wU, aU[li], 0, 0, 0);
                aV[li] = MFMA_F16(xf[li], wV, aV[li], 0, 0, 0);
            }
        }
#pragma unroll
        for (int m = 0; m < 2; ++m) {
            const _Float16* P = m ? P2 : P1;
#pragma unroll
            for (int i2 = 0; i2 < 4; ++i2) {
                int u = i2 * 256 + tid;
                int dd = u >> 5, seg = u & 31;
                *(half8*)(&Bh[m][dd * 264 + seg * 8]) = *(const half8*)(
                    P + ((size_t)(d0 + dd) * 1024 + f0) * 16 + seg * 8);
            }
        }
        __syncthreads();
        // ---- Phase B: mix(it) -> Wt  +  prefetch x frags (chunk it) ----
#pragma unroll
        for (int fl = 0; fl < 4; ++fl) {
            int f_l = w * 4 + fl;
#pragma unroll
            for (int dg = 0; dg < 2; ++dg) {
                half8 a1 = { 0, 0, 0, 0, 0, 0, 0, 0 };
                half8 a2 = { 0, 0, 0, 0, 0, 0, 0, 0 };
                if (kc < 2) {
                    a1 = *(const half8*)(&Bh[0][(dg * 16 + n) * 264 + f_l * 16 + kc * 8]);
                    a2 = *(const half8*)(&Bh[1][(dg * 16 + n) * 264 + f_l * 16 + kc * 8]);
                }
                f32x4 c1 = MFMA_F16(a1, cf1, zf, 0, 0, 0);
                nsqU[fl] += c1[0] * c1[0] + c1[1] * c1[1]
                          + c1[2] * c1[2] + c1[3] * c1[3];
                half4 h1 = { (_Float16)c1[0], (_Float16)c1[1],
                             (_Float16)c1[2], (_Float16)c1[3] };
                *(half4*)(&Wt[0][n * 648 + f_l * 40 + dg * 16 + kc * 4]) = h1;
                f32x4 c2 = MFMA_F16(a2, cf2, zf, 0, 0, 0);
                nsqV[fl] += c2[0] * c2[0] + c2[1] * c2[1]
                          + c2[2] * c2[2] + c2[3] * c2[3];
                half4 h2 = { (_Float16)c2[0], (_Float16)c2[1],
                             (_Float16)c2[2], (_Float16)c2[3] };
                *(half4*)(&Wt[1][n * 648 + f_l * 40 + dg * 16 + kc * 4]) = h2;
            }
        }
#pragma unroll
        for (int li = 0; li < 4; ++li) {
            int l = lg * 16 + w * 4 + li;
            const float* xp = x + ((size_t)n * 128 + l) * 512 + d0 + kc * 8;
            f32x4 v0 = *(const f32x4*)xp;
            f32x4 v1 = *(const f32x4*)(xp + 4);
            half8 h = { (_Float16)v0[0], (_Float16)v0[1], (_Float16)v0[2],
                        (_Float16)v0[3], (_Float16)v1[0], (_Float16)v1[1],
                        (_Float16)v1[2], (_Float16)v1[3] };
            xf[li] = h;
        }
        __syncthreads();
    }
    // ---- final consume (chunk 15) ----
#pragma unroll
    for (int li = 0; li < 4; ++li) {
        int l = w * 4 + li;
        half8 wU = *(const half8*)(&Wt[0][l * 648 + n * 40 + kc * 8]);
        half8 wV = *(const half8*)(&Wt[1][l * 648 + n * 40 + kc * 8]);
        aU[li] = MFMA_F16(xf[li], wU, aU[li], 0, 0, 0);
        aV[li] = MFMA_F16(xf[li], wV, aV[li], 0, 0, 0);
    }

    // ---- norms reduce ----
#pragma unroll
    for (int fl = 0; fl < 4; ++fl) {
        float vU = nsqU[fl], vV = nsqV[fl];
        vU += __shfl_xor(vU, 16); vU += __shfl_xor(vU, 32);
        vV += __shfl_xor(vV, 16); vV += __shfl_xor(vV, 32);
        if (kc == 0) {
            CN[0 * 256 + n * 16 + w * 4 + fl] = vU;
            CN[1 * 256 + n * 16 + w * 4 + fl] = vV;
        }
    }
    __syncthreads();

    int f = f0 + n;
    float usv = fabsf(usp[f]);
    float vsv = fabsf(vsp[f]) * 22.627416997969522f;   // sqrt(512)
#pragma unroll
    for (int li = 0; li < 4; ++li) {
        int lgl = lg * 16 + w * 4 + li;
        float r1 = 1.f / fmaxf(sqrtf(CN[0 * 256 + (w * 4 + li) * 16 + n]), 1e-12f);
        float r2 = 1.f / fmaxf(sqrtf(CN[1 * 256 + (w * 4 + li) * 16 + n]), 1e-12f);
#pragma unroll
        for (int i = 0; i < 4; ++i) {
            float u = aU[li][i] * r1;
            float v = aV[li][i] * r2;
            float zz = vsv * v;
            float sil = zz / (1.f + __expf(-zz));
            float h = sil * (usv * u);
            Hp[((size_t)lgl * 16 + kc * 4 + i) * 1024 + f] = (_Float16)h;
        }
    }
}

// ---------------------------------------------------------------------------
// down_fast: 512 blocks = 2 f-halves x 8 l-groups x 32 d-tiles, 256 threads.
// Writes partial sums Rp[zh][b][l][d] and partial col-norms Np[zh][l][d].
// ---------------------------------------------------------------------------
__global__ __launch_bounds__(256) void down_fast(
    const _Float16* __restrict__ P3, const float* __restrict__ tc3,
    const _Float16* __restrict__ Hp,
    float* __restrict__ Rp, float* __restrict__ Np)
{
    int zh = blockIdx.x >> 8;
    int rem = blockIdx.x & 255;
    int lg = rem >> 5;
    int d0 = (rem & 31) * 16;
    int tid = threadIdx.x;
    int w = tid >> 6, lane = tid & 63;
    int n = lane & 15, kc = lane >> 4;

    __shared__ __align__(16) _Float16 Bh[32 * 264];
    __shared__ __align__(16) _Float16 Wt[16 * 648];
    __shared__ float CN[256];

    if (tid < 16) {
        const float* row = tc3 + (size_t)(lg * 16 + tid) * 16;
        float e[16], m = -1e30f, sum = 0.f;
#pragma unroll
        for (int k = 0; k < 16; ++k) m = fmaxf(m, row[k]);
#pragma unroll
        for (int k = 0; k < 16; ++k) { e[k] = __expf(row[k] - m); sum += e[k]; }
        float r = 1.f / sum;
#pragma unroll
        for (int k = 0; k < 16; ++k) CN[tid * 16 + k] = e[k] * r;
    }
    __syncthreads();

    half8 cf3 = { 0, 0, 0, 0, 0, 0, 0, 0 };
    if (kc < 2) {
#pragma unroll
        for (int j = 0; j < 8; ++j)
            cf3[j] = (_Float16)CN[n * 16 + kc * 8 + j];
    }

    f32x4 zf = { 0.f, 0.f, 0.f, 0.f };
    f32x4 aO[4];
#pragma unroll
    for (int i = 0; i < 4; ++i) aO[i] = zf;
    float nsqD[4] = { 0.f, 0.f, 0.f, 0.f };
    half8 hf[4];

    for (int it = 0; it < 16; ++it) {
        int f0 = zh * 512 + it * 32;
        // ---- Phase A: consume(it-1) + stage Bh(it) ----
        if (it > 0) {
#pragma unroll
            for (int li = 0; li < 4; ++li) {
                int l = w * 4 + li;
                half8 wf = *(const half8*)(&Wt[l * 648 + n * 40 + kc * 8]);
                aO[li] = MFMA_F16(hf[li], wf, aO[li], 0, 0, 0);
            }
        }
#pragma unroll
        for (int i2 = 0; i2 < 4; ++i2) {
            int u = i2 * 256 + tid;
            int ff = u >> 5, seg = u & 31;
            *(half8*)(&Bh[ff * 264 + seg * 8]) = *(const half8*)(
                P3 + ((size_t)(f0 + ff) * 512 + d0) * 16 + seg * 8);
        }
        __syncthreads();
        // ---- Phase B: mix(it) -> Wt  +  prefetch Hp frags ----
#pragma unroll
        for (int dl = 0; dl < 4; ++dl) {
            int d_l = w * 4 + dl;
#pragma unroll
            for (int fg = 0; fg < 2; ++fg) {
                half8 a = { 0, 0, 0, 0, 0, 0, 0, 0 };
                if (kc < 2)
                    a = *(const half8*)(&Bh[(fg * 16 + n) * 264 + d_l * 16 + kc * 8]);
                f32x4 cw = MFMA_F16(a, cf3, zf, 0, 0, 0);
                nsqD[dl] += cw[0] * cw[0] + cw[1] * cw[1]
                          + cw[2] * cw[2] + cw[3] * cw[3];
                half4 h4 = { (_Float16)cw[0], (_Float16)cw[1],
                             (_Float16)cw[2], (_Float16)cw[3] };
                *(half4*)(&Wt[n * 648 + d_l * 40 + fg * 16 + kc * 4]) = h4;
            }
        }
#pragma unroll
        for (int li = 0; li < 4; ++li) {
            int l = lg * 16 + w * 4 + li;
            hf[li] = *(const half8*)(Hp + ((size_t)l * 16 + n) * 1024 + f0 + kc * 8);
        }
        __syncthreads();
    }
    // final consume
#pragma unroll
    for (int li = 0; li < 4; ++li) {
        int l = w * 4 + li;
        half8 wf = *(const half8*)(&Wt[l * 648 + n * 40 + kc * 8]);
        aO[li] = MFMA_F16(hf[li], wf, aO[li], 0, 0, 0);
    }

    // partial col-norms -> Np[zh][l][d]
#pragma unroll
    for (int dl = 0; dl < 4; ++dl) {
        float v = nsqD[dl];
        v += __shfl_xor(v, 16); v += __shfl_xor(v, 32);
        if (kc == 0)
            Np[(size_t)zh * 65536 + (size_t)(lg * 16 + n) * 512 + d0 + w * 4 + dl] = v;
    }
    // partial sums -> Rp[zh][b][l][d]
#pragma unroll
    for (int li = 0; li < 4; ++li) {
        int lgl = lg * 16 + w * 4 + li;
#pragma unroll
        for (int i = 0; i < 4; ++i)
            Rp[(size_t)zh * 1048576 +
               ((size_t)(kc * 4 + i) * 128 + lgl) * 512 + d0 + n] = aO[li][i];
    }
}

// ---------------------------------------------------------------------------
// final_combine: y = (Rp0+Rp1) * rsqrt(Np0+Np1) ; out = y / max(||y||,eps)
// ---------------------------------------------------------------------------
__global__ __launch_bounds__(128) void final_combine(
    const float* __restrict__ Rp, const float* __restrict__ Np,
    float* __restrict__ out)
{
    int rid = blockIdx.x;              // b*128 + l
    int l = rid & 127;
    int t = threadIdx.x;
    f32x4 r0 = *(const f32x4*)(Rp + (size_t)rid * 512 + t * 4);
    f32x4 r1 = *(const f32x4*)(Rp + 1048576 + (size_t)rid * 512 + t * 4);
    f32x4 n0 = *(const f32x4*)(Np + (size_t)l * 512 + t * 4);
    f32x4 n1 = *(const f32x4*)(Np + 65536 + (size_t)l * 512 + t * 4);
    f32x4 y;
#pragma unroll
    for (int j = 0; j < 4; ++j) {
        float rr = 1.f / fmaxf(sqrtf(fmaxf(n0[j] + n1[j], 0.f)), 1e-12f);
        y[j] = (r0[j] + r1[j]) * rr;
    }
    float s = y[0] * y[0] + y[1] * y[1] + y[2] * y[2] + y[3] * y[3];
#pragma unroll
    for (int off = 32; off > 0; off >>= 1) s += __shfl_down(s, off);
    __shared__ float sred[2];
    if ((t & 63) == 0) sred[t >> 6] = s;
    __syncthreads();
    float rr = 1.f / fmaxf(sqrtf(sred[0] + sred[1]), 1e-12f);
    f32x4 o = { y[0] * rr, y[1] * rr, y[2] * rr, y[3] * rr };
    *(f32x4*)(out + (size_t)rid * 512 + t * 4) = o;
}

// ===========================================================================
// SLOW FALLBACK (round-2 kernels, proven) — used when ws_size < WS_FAST
// ===========================================================================
__global__ __launch_bounds__(256) void up_kernel(
    const float* __restrict__ x,
    const float* __restrict__ wg, const float* __restrict__ wu,
    const float* __restrict__ tc1, const float* __restrict__ tc2,
    const float* __restrict__ usp, const float* __restrict__ vsp,
    _Float16* __restrict__ Hp)
{
    int lg = blockIdx.x >> 6;
    int f0 = (blockIdx.x & 63) * 16;
    int tid = threadIdx.x;
    int w = tid >> 6, lane = tid & 63;
    int n = lane & 15, kc = lane >> 4;

    __shared__ __align__(16) _Float16 Xt[256 * 40];
    __shared__ __align__(16) _Float16 Bh[32 * 16 * 24];
    __shared__ __align__(16) _Float16 Wt[16 * 528];
    __shared__ float CN[2 * 16 * 16];

    if (tid < 32) {
        int s = tid >> 4, ll = tid & 15;
        const float* row = (s ? tc2 : tc1) + (size_t)(lg * 16 + ll) * 16;
        float e[16], m = -1e30f, sum = 0.f;
#pragma unroll
        for (int k = 0; k < 16; ++k) m = fmaxf(m, row[k]);
#pragma unroll
        for (int k = 0; k < 16; ++k) { e[k] = __expf(row[k] - m); sum += e[k]; }
        float r = 1.f / sum;
#pragma unroll
        for (int k = 0; k < 16; ++k) CN[s * 256 + ll * 16 + k] = e[k] * r;
    }
    __syncthreads();

    half8 cf1 = { 0, 0, 0, 0, 0, 0, 0, 0 };
    half8 cf2 = { 0, 0, 0, 0, 0, 0, 0, 0 };
    if (kc < 2) {
#pragma unroll
        for (int j = 0; j < 8; ++j) {
            cf1[j] = (_Float16)CN[0 * 256 + n * 16 + kc * 8 + j];
            cf2[j] = (_Float16)CN[1 * 256 + n * 16 + kc * 8 + j];
        }
    }

    f32x4 zf = { 0.f, 0.f, 0.f, 0.f };
    f32x4 aU[4], aV[4];
#pragma unroll
    for (int i = 0; i < 4; ++i) { aU[i] = zf; aV[i] = zf; }
    float nsqU[4] = { 0.f, 0.f, 0.f, 0.f };
    float nsqV[4] = { 0.f, 0.f, 0.f, 0.f };

    for (int it = 0; it < 16; ++it) {
        int d0 = it * 32;
#pragma unroll
        for (int p = 0; p < 8; ++p) {
            int r = p * 32 + (tid >> 3);
            int fj = tid & 7;
            int ll = r >> 4, b = r & 15;
            f32x4 v = *(const f32x4*)(
                x + ((size_t)(b * 128 + lg * 16 + ll) * 512 + d0 + fj * 4));
            half4 h = { (_Float16)v[0], (_Float16)v[1],
                        (_Float16)v[2], (_Float16)v[3] };
            *(half4*)(&Xt[r * 40 + fj * 4]) = h;
        }
#pragma unroll
        for (int p = 0; p < 8; ++p) {
            int idx = p * 256 + tid;
            int q = idx & 3, dd = (idx >> 2) & 31, k = idx >> 7;
            f32x4 v = *(const f32x4*)(
                wg + ((size_t)k * 512 + d0 + dd) * 1024 + f0 + q * 4);
#pragma unroll
            for (int j = 0; j < 4; ++j)
                Bh[(dd * 16 + q * 4 + j) * 24 + k] = (_Float16)v[j];
        }
        __syncthreads();
#pragma unroll
        for (int fl = 0; fl < 4; ++fl) {
            int f_l = w * 4 + fl;
#pragma unroll
            for (int dg = 0; dg < 2; ++dg) {
                half8 a = { 0, 0, 0, 0, 0, 0, 0, 0 };
                if (kc < 2)
                    a = *(const half8*)(&Bh[((dg * 16 + n) * 16 + f_l) * 24 + kc * 8]);
                f32x4 cw = MFMA_F16(a, cf1, zf, 0, 0, 0);
                nsqU[fl] += cw[0] * cw[0] + cw[1] * cw[1]
                          + cw[2] * cw[2] + cw[3] * cw[3];
                half4 h4 = { (_Float16)cw[0], (_Float16)cw[1],
                             (_Float16)cw[2], (_Float16)cw[3] };
                *(half4*)(&Wt[n * 528 + f_l * 32 + dg * 16 + kc * 4]) = h4;
            }
        }
        __syncthreads();
#pragma unroll
        for (int li = 0; li < 4; ++li) {
            int l = w * 4 + li;
            half8 xf = *(const half8*)(&Xt[(l * 16 + n) * 40 + kc * 8]);
            half8 wf = *(const half8*)(&Wt[l * 528 + n * 32 + kc * 8]);
            aU[li] = MFMA_F16(xf, wf, aU[li], 0, 0, 0);
        }
#pragma unroll
        for (int p = 0; p < 8; ++p) {
            int idx = p * 256 + tid;
            int q = idx & 3, dd = (idx >> 2) & 31, k = idx >> 7;
            f32x4 v = *(const f32x4*)(
                wu + ((size_t)k * 512 + d0 + dd) * 1024 + f0 + q * 4);
#pragma unroll
            for (int j = 0; j < 4; ++j)
                Bh[(dd * 16 + q * 4 + j) * 24 + k] = (_Float16)v[j];
        }
        __syncthreads();
#pragma unroll
        for (int fl = 0; fl < 4; ++fl) {
            int f_l = w * 4 + fl;
#pragma unroll
            for (int dg = 0; dg < 2; ++dg) {
                half8 a = { 0, 0, 0, 0, 0, 0, 0, 0 };
                if (kc < 2)
                    a = *(const half8*)(&Bh[((dg * 16 + n) * 16 + f_l) * 24 + kc * 8]);
                f32x4 cw = MFMA_F16(a, cf2, zf, 0, 0, 0);
                nsqV[fl] += cw[0] * cw[0] + cw[1] * cw[1]
                          + cw[2] * cw[2] + cw[3] * cw[3];
                half4 h4 = { (_Float16)cw[0], (_Float16)cw[1],
                             (_Float16)cw[2], (_Float16)cw[3] };
                *(half4*)(&Wt[n * 528 + f_l * 32 + dg * 16 + kc * 4]) = h4;
            }
        }
        __syncthreads();
#pragma unroll
        for (int li = 0; li < 4; ++li) {
            int l = w * 4 + li;
            half8 xf = *(const half8*)(&Xt[(l * 16 + n) * 40 + kc * 8]);
            half8 wf = *(const half8*)(&Wt[l * 528 + n * 32 + kc * 8]);
            aV[li] = MFMA_F16(xf, wf, aV[li], 0, 0, 0);
        }
        __syncthreads();
    }

#pragma unroll
    for (int fl = 0; fl < 4; ++fl) {
        float vU = nsqU[fl], vV = nsqV[fl];
        vU += __shfl_xor(vU, 16); vU += __shfl_xor(vU, 32);
        vV += __shfl_xor(vV, 16); vV += __shfl_xor(vV, 32);
        if (kc == 0) {
            CN[0 * 256 + n * 16 + w * 4 + fl] = vU;
            CN[1 * 256 + n * 16 + w * 4 + fl] = vV;
        }
    }
    __syncthreads();

    int f = f0 + n;
    float usv = fabsf(usp[f]);
    float vsv = fabsf(vsp[f]) * 22.627416997969522f;
#pragma unroll
    for (int li = 0; li < 4; ++li) {
        int lgl = lg * 16 + w * 4 + li;
        float r1 = 1.f / fmaxf(sqrtf(CN[0 * 256 + (w * 4 + li) * 16 + n]), 1e-12f);
        float r2 = 1.f / fmaxf(sqrtf(CN[1 * 256 + (w * 4 + li) * 16 + n]), 1e-12f);
#pragma unroll
        for (int i = 0; i < 4; ++i) {
            float u = aU[li][i] * r1;
            float v = aV[li][i] * r2;
            float zz = vsv * v;
            float sil = zz / (1.f + __expf(-zz));
            float h = sil * (usv * u);
            Hp[((size_t)lgl * 16 + kc * 4 + i) * 1024 + f] = (_Float16)h;
        }
    }
}

__global__ __launch_bounds__(256) void down_kernel(
    const float* __restrict__ wd, const float* __restrict__ tc3,
    const _Float16* __restrict__ Hp, float* __restrict__ out)
{
    int lg = blockIdx.x >> 5;
    int d0 = (blockIdx.x & 31) * 16;
    int tid = threadIdx.x;
    int w = tid >> 6, lane = tid & 63;
    int n = lane & 15, kc = lane >> 4;

    __shared__ __align__(16) _Float16 Ht[256 * 40];
    __shared__ __align__(16) _Float16 Bh[32 * 16 * 24];
    __shared__ __align__(16) _Float16 Wt[16 * 528];
    __shared__ float CN[16 * 16];

    if (tid < 16) {
        const float* row = tc3 + (size_t)(lg * 16 + tid) * 16;
        float e[16], m = -1e30f, sum = 0.f;
#pragma unroll
        for (int k = 0; k < 16; ++k) m = fmaxf(m, row[k]);
#pragma unroll
        for (int k = 0; k < 16; ++k) { e[k] = __expf(row[k] - m); sum += e[k]; }
        float r = 1.f / sum;
#pragma unroll
        for (int k = 0; k < 16; ++k) CN[tid * 16 + k] = e[k] * r;
    }
    __syncthreads();

    half8 cf3 = { 0, 0, 0, 0, 0, 0, 0, 0 };
    if (kc < 2) {
#pragma unroll
        for (int j = 0; j < 8; ++j)
            cf3[j] = (_Float16)CN[n * 16 + kc * 8 + j];
    }

    f32x4 zf = { 0.f, 0.f, 0.f, 0.f };
    f32x4 aO[4];
#pragma unroll
    for (int i = 0; i < 4; ++i) aO[i] = zf;
    float nsqD[4] = { 0.f, 0.f, 0.f, 0.f };

    for (int it = 0; it < 32; ++it) {
        int f0 = it * 32;
#pragma unroll
        for (int p = 0; p < 8; ++p) {
            int r = p * 32 + (tid >> 3);
            int hj = tid & 7;
            int ll = r >> 4, b = r & 15;
            half4 v = *(const half4*)(
                Hp + ((size_t)(lg * 16 + ll) * 16 + b) * 1024 + f0 + hj * 4);
            *(half4*)(&Ht[r * 40 + hj * 4]) = v;
        }
#pragma unroll
        for (int p = 0; p < 8; ++p) {
            int idx = p * 256 + tid;
            int q = idx & 3, ff = (idx >> 2) & 31, k = idx >> 7;
            f32x4 v = *(const f32x4*)(
                wd + ((size_t)k * 1024 + f0 + ff) * 512 + d0 + q * 4);
#pragma unroll
            for (int j = 0; j < 4; ++j)
                Bh[(ff * 16 + q * 4 + j) * 24 + k] = (_Float16)v[j];
        }
        __syncthreads();
#pragma unroll
        for (int dl = 0; dl < 4; ++dl) {
            int d_l = w * 4 + dl;
#pragma unroll
            for (int fg = 0; fg < 2; ++fg) {
                half8 a = { 0, 0, 0, 0, 0, 0, 0, 0 };
                if (kc < 2)
                    a = *(const half8*)(&Bh[((fg * 16 + n) * 16 + d_l) * 24 + kc * 8]);
                f32x4 cw = MFMA_F16(a, cf3, zf, 0, 0, 0);
                nsqD[dl] += cw[0] * cw[0] + cw[1] * cw[1]
                          + cw[2] * cw[2] + cw[3] * cw[3];
                half4 h4 = { (_Float16)cw[0], (_Float16)cw[1],
                             (_Float16)cw[2], (_Float16)cw[3] };
                *(half4*)(&Wt[n * 528 + d_l * 32 + fg * 16 + kc * 4]) = h4;
            }
        }
        __syncthreads();
#pragma unroll
        for (int li = 0; li < 4; ++li) {
            int l = w * 4 + li;
            half8 hf = *(const half8*)(&Ht[(l * 16 + n) * 40 + kc * 8]);
            half8 wf = *(const half8*)(&Wt[l * 528 + n * 32 + kc * 8]);
            aO[li] = MFMA_F16(hf, wf, aO[li], 0, 0, 0);
        }
        __syncthreads();
    }

#pragma unroll
    for (int dl = 0; dl < 4; ++dl) {
        float v = nsqD[dl];
        v += __shfl_xor(v, 16); v += __shfl_xor(v, 32);
        if (kc == 0) CN[n * 16 + w * 4 + dl] = v;
    }
    __syncthreads();

#pragma unroll
    for (int li = 0; li < 4; ++li) {
        int lgl = lg * 16 + w * 4 + li;
        float r3 = 1.f / fmaxf(sqrtf(CN[(w * 4 + li) * 16 + n]), 1e-12f);
#pragma unroll
        for (int i = 0; i < 4; ++i)
            out[((size_t)(kc * 4 + i) * 128 + lgl) * 512 + d0 + n] = aO[li][i] * r3;
    }
}

__global__ __launch_bounds__(128) void final_kernel(float* __restrict__ out)
{
    int rid = blockIdx.x;
    int t = threadIdx.x;
    f32x4 y = *(const f32x4*)(out + (size_t)rid * 512 + t * 4);
    float s = y[0] * y[0] + y[1] * y[1] + y[2] * y[2] + y[3] * y[3];
#pragma unroll
    for (int off = 32; off > 0; off >>= 1) s += __shfl_down(s, off);
    __shared__ float sred[2];
    if ((t & 63) == 0) sred[t >> 6] = s;
    __syncthreads();
    float rr = 1.f / fmaxf(sqrtf(sred[0] + sred[1]), 1e-12f);
    f32x4 o = { y[0] * rr, y[1] * rr, y[2] * rr, y[3] * rr };
    *(f32x4*)(out + (size_t)rid * 512 + t * 4) = o;
}

// ---------------------------------------------------------------------------
extern "C" void kernel_launch(void* const* d_in, const int* in_sizes, int n_in,
                              void* d_out, int out_size, void* d_ws, size_t ws_size,
                              hipStream_t stream)
{
    (void)in_sizes; (void)n_in; (void)out_size;
    const float* x   = (const float*)d_in[0];
    const float* wg  = (const float*)d_in[1];
    const float* wu  = (const float*)d_in[2];
    const float* wd  = (const float*)d_in[3];
    const float* tc1 = (const float*)d_in[4];
    const float* tc2 = (const float*)d_in[5];
    const float* tc3 = (const float*)d_in[6];
    const float* usp = (const float*)d_in[7];
    const float* vsp = (const float*)d_in[8];
    float* outp = (float*)d_out;
    char* ws = (char*)d_ws;

    if (ws_size >= WS_FAST) {
        _Float16* P1 = (_Float16*)(ws + OFF_P1);
        _Float16* P2 = (_Float16*)(ws + OFF_P2);
        _Float16* P3 = (_Float16*)(ws + OFF_P3);
        _Float16* Hp = (_Float16*)(ws + OFF_HP);
        float* Rp = (float*)(ws + OFF_P1);   // overlays P1 (dead after up)
        float* Np = (float*)(ws + OFF_P2);   // overlays P2 (dead after up)
        prep_basis_all<<<dim3(2048, 3), dim3(256), 0, stream>>>(wg, wu, wd,
                                                                P1, P2, P3);
        up_fast<<<dim3(512), dim3(256), 0, stream>>>(P1, P2, x, tc1, tc2,
                                                     usp, vsp, Hp);
        down_fast<<<dim3(512), dim3(256), 0, stream>>>(P3, tc3, Hp, Rp, Np);
        final_combine<<<dim3(2048), dim3(128), 0, stream>>>(Rp, Np, outp);
    } else {
        _Float16* Hp = (_Float16*)ws;
        up_kernel<<<dim3(512), dim3(256), 0, stream>>>(x, wg, wu, tc1, tc2,
                                                       usp, vsp, Hp);
        down_kernel<<<dim3(256), dim3(256), 0, stream>>>(wd, tc3, Hp, outp);
        final_kernel<<<dim3(2048), dim3(128), 0, stream>>>(outp);
    }
}